// Round 1
// baseline (108.107 us; speedup 1.0000x reference)
//
#include <hip/hip_runtime.h>
#include <hip/hip_bf16.h>

// VQ: latents [32,64,64,64] f32 (B,D,H,W), embedding [1024,64] f32.
// out = concat( quantized [32,64,64,64] f32 , vq_loss scalar ).
// N = 131072 positions, D = 64, K = 1024.
//
// Fused design: codebook (-2E, bf16, row-rotate swizzled) lives ENTIRELY in
// LDS (128 KB) -> barrier-free K-loop of MFMA 16x16x32 with C-init = 1+||e||^2.
// Encoded argmin: enc = (bits(score) & ~1023) | code ; v_min3_u32 trees.
// Epilogue gathers quantized values from the LDS bf16 codebook (out = -0.5 *
// bf16(-2e), ~2e-6 error) with fully coalesced f32x4 stores. One block per CU.
//
// R1 change vs 106.2us baseline: 8 waves x 64 positions (was 16 x 32).
// Halves per-CU LDS codebook read traffic in the K-loop (each A-fragment
// read now feeds 8 MFMAs instead of 4) and doubles per-wave ILP (4
// independent acc chains), trading TLP (2 waves/SIMD) for ILP.

#define HW 4096
#define OUTELEMS 8388608

typedef __attribute__((ext_vector_type(8))) short bf16x8;
typedef __attribute__((ext_vector_type(4))) float f32x4;
typedef __attribute__((ext_vector_type(4))) int i32x4;

static __device__ __forceinline__ short f2bf(float f) {
    union { __hip_bfloat16 h; short s; } u;
    u.h = __float2bfloat16(f);
    return u.s;
}
static __device__ __forceinline__ unsigned umin2(unsigned a, unsigned b) {
    return a < b ? a : b;
}

// ws layout:
//   [0, 131072)        Ebf: -2*E bf16, row-rotate-swizzled (1024 rows x 128 B)
//   [131072, 135168)   en1: 1 + ||e||^2 f32 (1024)

__global__ __launch_bounds__(256) void prep_kernel(const float* __restrict__ emb,
                                                   short* __restrict__ Ebf,
                                                   float* __restrict__ en1,
                                                   float* __restrict__ loss) {
    int code = blockIdx.x * 4 + (threadIdx.x >> 6);
    int d = threadIdx.x & 63;
    float v = emb[code * 64 + d];
    int g = d >> 3, j = d & 7;
    // row-rotate swizzle: d-group g of row `code` stored at slot (g+code)&7
    Ebf[code * 64 + ((g + code) & 7) * 8 + j] = f2bf(-2.0f * v);
    float s = v * v;
#pragma unroll
    for (int off = 32; off > 0; off >>= 1) s += __shfl_xor(s, off, 64);
    if (d == 0) en1[code] = 1.0f + s;
    if (blockIdx.x == 0 && threadIdx.x == 0) *loss = 0.0f;
}

// 256 blocks x 512 threads (8 waves). Block: 512 positions, full K=1024.
// Dynamic LDS: [0,131072) codebook ; [131072,135168) en1 ;
//              [135168,137216) codes i32[512] ; [137216,137248) wave loss sums.
__global__ __launch_bounds__(512, 2) void vq_kernel(
        const float* __restrict__ lat, const short* __restrict__ Ebf,
        const float* __restrict__ en1, float* __restrict__ out,
        float* __restrict__ loss) {
    extern __shared__ __align__(16) char sbuf[];
    const int tid  = threadIdx.x;
    const int wave = tid >> 6;
    const int lane = tid & 63;
    const int n    = lane & 15;
    const int quad = lane >> 4;

    const int g0 = blockIdx.x * 512;
    const int b  = g0 >> 12;
    const int mb = g0 & 4095;
    const float* latb = lat + (size_t)b * 262144;

    // ---- stage full codebook + en1 into LDS (once) ----
    {
        const f32x4* src = (const f32x4*)Ebf;
        f32x4* dst = (f32x4*)sbuf;
#pragma unroll
        for (int r = 0; r < 16; ++r)
            dst[r * 512 + tid] = src[r * 512 + tid];
        if (tid < 256)
            ((f32x4*)(sbuf + 131072))[tid] = ((const f32x4*)en1)[tid];
    }

    // ---- X fragments: 64 positions/wave + fp32 ||x||^2 ----
    bf16x8 bfr[4][2];
    float xnorm[4];
#pragma unroll
    for (int s = 0; s < 4; ++s) {
        const float* xp = latb + (mb + wave * 64 + s * 16 + n);
        float xs = 0.0f; bf16x8 f0, f1;
#pragma unroll
        for (int j = 0; j < 8; ++j) {
            float x0 = xp[(quad * 8 + j) * HW];
            float x1 = xp[(32 + quad * 8 + j) * HW];
            xs += x0 * x0 + x1 * x1;
            f0[j] = f2bf(x0); f1[j] = f2bf(x1);
        }
        bfr[s][0] = f0; bfr[s][1] = f1; xnorm[s] = xs;
    }
    __syncthreads();

    // ---- barrier-free K-loop over all 1024 codes ----
    const int slot0 = ((quad + n) & 7) * 16;
    const int slot1 = ((quad + 4 + n) & 7) * 16;
    const char* arowBase = sbuf + n * 128;
    const f32x4* enl = (const f32x4*)(sbuf + 131072);
    unsigned emin[4] = {0xFFFFFFFFu, 0xFFFFFFFFu, 0xFFFFFFFFu, 0xFFFFFFFFu};

#pragma unroll 2
    for (int ct = 0; ct < 64; ++ct) {
        const char* rb = arowBase + ct * 2048;
        bf16x8 a0 = *(const bf16x8*)(rb + slot0);
        bf16x8 a1 = *(const bf16x8*)(rb + slot1);
        f32x4 en4 = enl[ct * 4 + quad];
        const unsigned cb = ct * 16 + quad * 4;
#pragma unroll
        for (int s = 0; s < 4; ++s) {
            f32x4 acc = __builtin_amdgcn_mfma_f32_16x16x32_bf16(a0, bfr[s][0], en4, 0, 0, 0);
            acc = __builtin_amdgcn_mfma_f32_16x16x32_bf16(a1, bfr[s][1], acc, 0, 0, 0);
            unsigned e0 = (__float_as_uint(acc[0]) & 0xFFFFFC00u) | (cb + 0);
            unsigned e1 = (__float_as_uint(acc[1]) & 0xFFFFFC00u) | (cb + 1);
            unsigned e2 = (__float_as_uint(acc[2]) & 0xFFFFFC00u) | (cb + 2);
            unsigned e3 = (__float_as_uint(acc[3]) & 0xFFFFFC00u) | (cb + 3);
            emin[s] = umin2(emin[s], umin2(umin2(e0, e1), umin2(e2, e3)));
        }
    }

    // ---- cross-quad reduce (min enc, sum xnorm) ----
#pragma unroll
    for (int off = 16; off <= 32; off <<= 1) {
#pragma unroll
        for (int s = 0; s < 4; ++s) {
            unsigned eo = (unsigned)__shfl_xor((int)emin[s], off, 64);
            float xo = __shfl_xor(xnorm[s], off, 64);
            emin[s] = eo < emin[s] ? eo : emin[s];
            xnorm[s] += xo;
        }
    }

    int* codes = (int*)(sbuf + 135168);
    if (quad == 0) {
#pragma unroll
        for (int s = 0; s < 4; ++s)
            codes[wave * 64 + s * 16 + n] = (int)(emin[s] & 1023u);
    }

    // per-position dist = (score - 1) + ||x||^2 ; each position in 4 lanes
    float contrib = 0.0f;
#pragma unroll
    for (int s = 0; s < 4; ++s)
        contrib += __uint_as_float(emin[s] & 0xFFFFFC00u) - 1.0f + xnorm[s];
#pragma unroll
    for (int off = 32; off > 0; off >>= 1) contrib += __shfl_xor(contrib, off, 64);
    float* wsum = (float*)(sbuf + 137216);
    if (lane == 0) wsum[wave] = contrib;
    __syncthreads();
    if (tid == 0) {
        float t = 0.0f;
#pragma unroll
        for (int w = 0; w < 8; ++w) t += wsum[w];
        atomicAdd(loss, t * (1.25f / (8388608.0f * 4.0f)));
    }

    // ---- fused gather epilogue: LDS codebook -> coalesced f32x4 stores ----
    float* outb = out + (size_t)b * 262144 + mb;
#pragma unroll 2
    for (int i = 0; i < 16; ++i) {
        int id = i * 512 + tid;        // 0..8191
        int d  = id >> 7;              // 0..63 (fixed per 128 threads)
        int mq = (id & 127) * 4;       // position group of 4
        i32x4 c4 = *(const i32x4*)(codes + mq);
        int g = d >> 3, j2 = (d & 7) * 2;
        unsigned u0 = *(const unsigned short*)(sbuf + c4.x * 128 + ((g + c4.x) & 7) * 16 + j2);
        unsigned u1 = *(const unsigned short*)(sbuf + c4.y * 128 + ((g + c4.y) & 7) * 16 + j2);
        unsigned u2 = *(const unsigned short*)(sbuf + c4.z * 128 + ((g + c4.z) & 7) * 16 + j2);
        unsigned u3 = *(const unsigned short*)(sbuf + c4.w * 128 + ((g + c4.w) & 7) * 16 + j2);
        f32x4 v;
        v[0] = __uint_as_float(u0 << 16) * -0.5f;
        v[1] = __uint_as_float(u1 << 16) * -0.5f;
        v[2] = __uint_as_float(u2 << 16) * -0.5f;
        v[3] = __uint_as_float(u3 << 16) * -0.5f;
        *(f32x4*)(outb + d * HW + mq) = v;
    }
}

extern "C" void kernel_launch(void* const* d_in, const int* in_sizes, int n_in,
                              void* d_out, int out_size, void* d_ws, size_t ws_size,
                              hipStream_t stream) {
    const float* latents   = (const float*)d_in[0];
    const float* embedding = (const float*)d_in[1];
    float* out  = (float*)d_out;
    float* loss = out + OUTELEMS;

    char* ws = (char*)d_ws;
    short* Ebf = (short*)ws;
    float* en1 = (float*)(ws + 131072);

    hipFuncSetAttribute((const void*)vq_kernel,
                        hipFuncAttributeMaxDynamicSharedMemorySize, 137280);

    prep_kernel<<<256, 256, 0, stream>>>(embedding, Ebf, en1, loss);
    vq_kernel<<<256, 512, 137280, stream>>>(latents, Ebf, en1, out, loss);
}

// Round 2
// 104.288 us; speedup vs baseline: 1.0366x; 1.0366x over previous
//
#include <hip/hip_runtime.h>
#include <hip/hip_bf16.h>

// VQ: latents [32,64,64,64] f32 (B,D,H,W), embedding [1024,64] f32.
// out = concat( quantized [32,64,64,64] f32 , vq_loss scalar ).
// N = 131072 positions, D = 64, K = 1024.
//
// Fused design: codebook (-2E, bf16, row-rotate swizzled) lives ENTIRELY in
// LDS (128 KB) -> barrier-free K-loop of MFMA 16x16x32 with C-init = 1+||e||^2.
// Encoded argmin: enc = (bits(score) & ~1023) | code ; v_min3_u32 trees.
// Epilogue gathers quantized values from the LDS bf16 codebook (out = -0.5 *
// bf16(-2e), ~2e-6 error) with fully coalesced f32x4 stores. One block per CU.
//
// R2: measured reality — harness re-poison fills (~87us of 108us) dominate
// dur_us; vq_kernel itself is <42us (absent from rocprof top-5). Optimize the
// controllable latency-bound phases:
//  - back to 16 waves (1024 thr): TLP wins in global phases (106.2 vs 108.1)
//  - epilogue: u32 pair-gather (d, d+1 per LDS read) halves gather ops
//  - linearized min-chain -> v_min3_u32 in encode
//  - loss atomic moved after the store loop

#define HW 4096
#define OUTELEMS 8388608

typedef __attribute__((ext_vector_type(8))) short bf16x8;
typedef __attribute__((ext_vector_type(4))) float f32x4;
typedef __attribute__((ext_vector_type(4))) int i32x4;

static __device__ __forceinline__ short f2bf(float f) {
    union { __hip_bfloat16 h; short s; } u;
    u.h = __float2bfloat16(f);
    return u.s;
}
static __device__ __forceinline__ unsigned umin2(unsigned a, unsigned b) {
    return a < b ? a : b;
}

// ws layout:
//   [0, 131072)        Ebf: -2*E bf16, row-rotate-swizzled (1024 rows x 128 B)
//   [131072, 135168)   en1: 1 + ||e||^2 f32 (1024)

__global__ __launch_bounds__(256) void prep_kernel(const float* __restrict__ emb,
                                                   short* __restrict__ Ebf,
                                                   float* __restrict__ en1,
                                                   float* __restrict__ loss) {
    int code = blockIdx.x * 4 + (threadIdx.x >> 6);
    int d = threadIdx.x & 63;
    float v = emb[code * 64 + d];
    int g = d >> 3, j = d & 7;
    // row-rotate swizzle: d-group g of row `code` stored at slot (g+code)&7
    Ebf[code * 64 + ((g + code) & 7) * 8 + j] = f2bf(-2.0f * v);
    float s = v * v;
#pragma unroll
    for (int off = 32; off > 0; off >>= 1) s += __shfl_xor(s, off, 64);
    if (d == 0) en1[code] = 1.0f + s;
    if (blockIdx.x == 0 && threadIdx.x == 0) *loss = 0.0f;
}

// 256 blocks x 1024 threads (16 waves). Block: 512 positions, full K=1024.
// Dynamic LDS: [0,131072) codebook ; [131072,135168) en1 ;
//              [135168,137216) codes i32[512] ; [137216,137280) wave loss sums.
__global__ __launch_bounds__(1024, 4) void vq_kernel(
        const float* __restrict__ lat, const short* __restrict__ Ebf,
        const float* __restrict__ en1, float* __restrict__ out,
        float* __restrict__ loss) {
    extern __shared__ __align__(16) char sbuf[];
    const int tid  = threadIdx.x;
    const int wave = tid >> 6;
    const int lane = tid & 63;
    const int n    = lane & 15;
    const int quad = lane >> 4;

    const int g0 = blockIdx.x * 512;
    const int b  = g0 >> 12;
    const int mb = g0 & 4095;
    const float* latb = lat + (size_t)b * 262144;

    // ---- stage full codebook + en1 into LDS (once) ----
    {
        const f32x4* src = (const f32x4*)Ebf;
        f32x4* dst = (f32x4*)sbuf;
#pragma unroll
        for (int r = 0; r < 8; ++r)
            dst[r * 1024 + tid] = src[r * 1024 + tid];
        if (tid < 256)
            ((f32x4*)(sbuf + 131072))[tid] = ((const f32x4*)en1)[tid];
    }

    // ---- X fragments: 32 positions/wave + fp32 ||x||^2 ----
    bf16x8 bfr[2][2];
    float xnorm[2];
#pragma unroll
    for (int s = 0; s < 2; ++s) {
        const float* xp = latb + (mb + wave * 32 + s * 16 + n);
        float xs = 0.0f; bf16x8 f0, f1;
#pragma unroll
        for (int j = 0; j < 8; ++j) {
            float x0 = xp[(quad * 8 + j) * HW];
            float x1 = xp[(32 + quad * 8 + j) * HW];
            xs += x0 * x0 + x1 * x1;
            f0[j] = f2bf(x0); f1[j] = f2bf(x1);
        }
        bfr[s][0] = f0; bfr[s][1] = f1; xnorm[s] = xs;
    }
    __syncthreads();

    // ---- barrier-free K-loop over all 1024 codes ----
    const int slot0 = ((quad + n) & 7) * 16;
    const int slot1 = ((quad + 4 + n) & 7) * 16;
    const char* arowBase = sbuf + n * 128;
    const f32x4* enl = (const f32x4*)(sbuf + 131072);
    unsigned emin[2] = {0xFFFFFFFFu, 0xFFFFFFFFu};

#pragma unroll 2
    for (int ct = 0; ct < 64; ++ct) {
        const char* rb = arowBase + ct * 2048;
        bf16x8 a0 = *(const bf16x8*)(rb + slot0);
        bf16x8 a1 = *(const bf16x8*)(rb + slot1);
        f32x4 en4 = enl[ct * 4 + quad];
        const unsigned cb = ct * 16 + quad * 4;
#pragma unroll
        for (int s = 0; s < 2; ++s) {
            f32x4 acc = __builtin_amdgcn_mfma_f32_16x16x32_bf16(a0, bfr[s][0], en4, 0, 0, 0);
            acc = __builtin_amdgcn_mfma_f32_16x16x32_bf16(a1, bfr[s][1], acc, 0, 0, 0);
            unsigned e0 = (__float_as_uint(acc[0]) & 0xFFFFFC00u) | (cb + 0);
            unsigned e1 = (__float_as_uint(acc[1]) & 0xFFFFFC00u) | (cb + 1);
            unsigned e2 = (__float_as_uint(acc[2]) & 0xFFFFFC00u) | (cb + 2);
            unsigned e3 = (__float_as_uint(acc[3]) & 0xFFFFFC00u) | (cb + 3);
            // linear chain -> 2x v_min3_u32
            emin[s] = umin2(umin2(umin2(umin2(e0, e1), e2), e3), emin[s]);
        }
    }

    // ---- cross-quad reduce (min enc, sum xnorm) ----
#pragma unroll
    for (int off = 16; off <= 32; off <<= 1) {
#pragma unroll
        for (int s = 0; s < 2; ++s) {
            unsigned eo = (unsigned)__shfl_xor((int)emin[s], off, 64);
            float xo = __shfl_xor(xnorm[s], off, 64);
            emin[s] = eo < emin[s] ? eo : emin[s];
            xnorm[s] += xo;
        }
    }

    int* codes = (int*)(sbuf + 135168);
    if (quad == 0) {
        codes[wave * 32 + n]      = (int)(emin[0] & 1023u);
        codes[wave * 32 + 16 + n] = (int)(emin[1] & 1023u);
    }

    // per-position dist = (score - 1) + ||x||^2 ; each position in 4 lanes
    float contrib = 0.0f;
#pragma unroll
    for (int s = 0; s < 2; ++s)
        contrib += __uint_as_float(emin[s] & 0xFFFFFC00u) - 1.0f + xnorm[s];
#pragma unroll
    for (int off = 32; off > 0; off >>= 1) contrib += __shfl_xor(contrib, off, 64);
    float* wsum = (float*)(sbuf + 137216);
    if (lane == 0) wsum[wave] = contrib;
    __syncthreads();

    // ---- fused gather epilogue: LDS codebook -> coalesced f32x4 stores ----
    // u32 pair-gather: each LDS read yields bf16 for d (low) and d+1 (high).
    float* outb = out + (size_t)b * 262144 + mb;
#pragma unroll 2
    for (int i = 0; i < 4; ++i) {
        int id = i * 1024 + tid;       // 0..4095
        int dp = id >> 7;              // 0..31 (d-pair index)
        int d  = dp * 2;               // even d
        int mq = (id & 127) * 4;       // position group of 4
        i32x4 c4 = *(const i32x4*)(codes + mq);
        int g = d >> 3, j2 = (d & 7) * 2;   // j2 in {0,4,8,12}, 4B-aligned
        unsigned u0 = *(const unsigned*)(sbuf + c4.x * 128 + ((g + c4.x) & 7) * 16 + j2);
        unsigned u1 = *(const unsigned*)(sbuf + c4.y * 128 + ((g + c4.y) & 7) * 16 + j2);
        unsigned u2 = *(const unsigned*)(sbuf + c4.z * 128 + ((g + c4.z) & 7) * 16 + j2);
        unsigned u3 = *(const unsigned*)(sbuf + c4.w * 128 + ((g + c4.w) & 7) * 16 + j2);
        f32x4 vlo, vhi;
        vlo[0] = __uint_as_float(u0 << 16) * -0.5f;
        vlo[1] = __uint_as_float(u1 << 16) * -0.5f;
        vlo[2] = __uint_as_float(u2 << 16) * -0.5f;
        vlo[3] = __uint_as_float(u3 << 16) * -0.5f;
        vhi[0] = __uint_as_float(u0 & 0xFFFF0000u) * -0.5f;
        vhi[1] = __uint_as_float(u1 & 0xFFFF0000u) * -0.5f;
        vhi[2] = __uint_as_float(u2 & 0xFFFF0000u) * -0.5f;
        vhi[3] = __uint_as_float(u3 & 0xFFFF0000u) * -0.5f;
        *(f32x4*)(outb + d * HW + mq)       = vlo;
        *(f32x4*)(outb + (d + 1) * HW + mq) = vhi;
    }

    if (tid == 0) {
        float t = 0.0f;
#pragma unroll
        for (int w = 0; w < 16; ++w) t += wsum[w];
        atomicAdd(loss, t * (1.25f / (8388608.0f * 4.0f)));
    }
}

extern "C" void kernel_launch(void* const* d_in, const int* in_sizes, int n_in,
                              void* d_out, int out_size, void* d_ws, size_t ws_size,
                              hipStream_t stream) {
    const float* latents   = (const float*)d_in[0];
    const float* embedding = (const float*)d_in[1];
    float* out  = (float*)d_out;
    float* loss = out + OUTELEMS;

    char* ws = (char*)d_ws;
    short* Ebf = (short*)ws;
    float* en1 = (float*)(ws + 131072);

    hipFuncSetAttribute((const void*)vq_kernel,
                        hipFuncAttributeMaxDynamicSharedMemorySize, 137280);

    prep_kernel<<<256, 256, 0, stream>>>(embedding, Ebf, en1, loss);
    vq_kernel<<<256, 1024, 137280, stream>>>(latents, Ebf, en1, out, loss);
}